// Round 5
// baseline (466.083 us; speedup 1.0000x reference)
//
#include <hip/hip_runtime.h>

// ---------------------------------------------------------------------------
// ConvRNN GCN cell — bf16-MFMA GEMMs + bucketed counting-sort CSR +
// XCD-column-partitioned gather aggregation.
//   1. setup: Wt/Vt bf16 transpose + zero bucket counters + edge dtype detect
//   2. bucket_count: per-block LDS hist of dst>>9 -> bucket_cnt (196 buckets)
//   3. bucket_scan:  exclusive scan -> bucket_base (CSR coords)
//   4. partition:    scatter packed (src|dlocal<<20) recs into bucket regions
//   5. bucket_fill:  per-bucket LDS degree hist + scan -> off/degcnt/dinv
//                    (coalesced) + exact CSR scatter via LDS atomics
//   6. GEMM1 (MFMA): hsg[g][n][16] = bf16((([x|hid]@W) * dinv[row])[16g..16g+15])
//   7. aggregate: group g = blockIdx&7 -> one XCD owns 16 cols (3.2MB, L2-fit);
//      nh = sigmoid(b + (sum_src hsg[g][src] + hsg[g][n])*dinv[n] + bias)
//   8. GEMM2 (MFMA): o = cmat + bf16(nh) @ V   (reads nh f32 from d_out)
// Requires N <= 2^20 (packed recs). No random global atomics anywhere.
// ---------------------------------------------------------------------------

typedef __attribute__((ext_vector_type(8))) short bf16x8;
typedef __attribute__((ext_vector_type(4))) short s16x4;
typedef __attribute__((ext_vector_type(4))) float f32x4;

__device__ __forceinline__ unsigned short f2bf(float f) {
    unsigned int u = __float_as_uint(f);
    unsigned int r = u + 0x7fffu + ((u >> 16) & 1u);   // round-to-nearest-even
    return (unsigned short)(r >> 16);
}
__device__ __forceinline__ float bflo(unsigned int u) { return __uint_as_float(u << 16); }
__device__ __forceinline__ float bfhi(unsigned int u) { return __uint_as_float(u & 0xffff0000u); }

// blocks 0..127: Wt transpose; 128..191: Vt transpose; 192: zero counters + dtype detect
__global__ __launch_bounds__(256) void setup_kernel(
    const float* __restrict__ W, const float* __restrict__ V,
    unsigned short* __restrict__ Wt, unsigned short* __restrict__ Vt,
    unsigned int* __restrict__ bucket_cnt /*512 words: cnt+cursor*/,
    const unsigned int* __restrict__ eraw, long long twoE, int* __restrict__ flag)
{
    __shared__ int nz;
    const int b = blockIdx.x;
    const int t = threadIdx.x;
    if (b < 128) {
        int idx = b * 256 + t;            // 32768 = 256*128
        int c = idx >> 8, k = idx & 255;
        Wt[c * 256 + k] = f2bf(W[k * 128 + c]);
    } else if (b < 192) {
        int j = (b - 128) * 256 + t;      // 16384 = 128*128
        int c = j >> 7, k = j & 127;
        Vt[c * 128 + k] = f2bf(V[k * 128 + c]);
    } else {
        bucket_cnt[t] = 0u;
        bucket_cnt[t + 256] = 0u;
        if (t == 0) nz = 0;
        __syncthreads();
        long long i = 2LL * t + 1;
        if (i < twoE && eraw[i] != 0u) nz = 1;
        __syncthreads();
        if (t == 0) *flag = (nz == 0) ? 1 : 0;
    }
}

// per-block LDS histogram of dst buckets -> global bucket_cnt
__global__ __launch_bounds__(256) void bucket_count_kernel(
    const void* __restrict__ eraw, const int* __restrict__ flag,
    unsigned int* __restrict__ bucket_cnt, long long E, int N)
{
    __shared__ unsigned int hist[256];
    const int t = threadIdx.x;
    hist[t] = 0u;
    __syncthreads();
    const int is64 = *flag;
    long long i0 = (long long)blockIdx.x * 8192;
    long long iend = i0 + 8192; if (iend > E) iend = E;
    if (is64) {
        const long long* dp = (const long long*)eraw + E;
        for (long long i = i0 + t; i < iend; i += 256) {
            int d = (int)dp[i];
            d = d < 0 ? 0 : (d >= N ? N - 1 : d);
            atomicAdd(&hist[d >> 9], 1u);
        }
    } else {
        const int* dp = (const int*)eraw + E;
        for (long long i = i0 + t; i < iend; i += 256) {
            int d = dp[i];
            d = d < 0 ? 0 : (d >= N ? N - 1 : d);
            atomicAdd(&hist[d >> 9], 1u);
        }
    }
    __syncthreads();
    unsigned int h = hist[t];
    if (h) atomicAdd(&bucket_cnt[t], h);
}

// exclusive scan of <=256 bucket counts; base[nbkt] = E
__global__ void bucket_scan_kernel(const unsigned int* __restrict__ cnt,
                                   unsigned int* __restrict__ base,
                                   int nbkt, unsigned int Etot) {
    __shared__ unsigned int s[256];
    int t = threadIdx.x;
    unsigned int v = (t < nbkt) ? cnt[t] : 0u;
    s[t] = v;
    __syncthreads();
    for (int o = 1; o < 256; o <<= 1) {
        unsigned int x = (t >= o) ? s[t - o] : 0u;
        __syncthreads();
        s[t] += x;
        __syncthreads();
    }
    if (t < nbkt) base[t] = s[t] - v;
    if (t == 0) base[nbkt] = Etot;
}

// scatter packed (src | dlocal<<20) records into bucket regions
__global__ __launch_bounds__(256) void partition_kernel(
    const void* __restrict__ eraw, const int* __restrict__ flag,
    const unsigned int* __restrict__ bucket_base,
    unsigned int* __restrict__ bucket_cursor,
    unsigned int* __restrict__ recs, long long E, int N)
{
    __shared__ unsigned int hist[256];
    __shared__ unsigned int base[256];
    const int t = threadIdx.x;
    hist[t] = 0u;
    __syncthreads();
    const int is64 = *flag;
    long long i0 = (long long)blockIdx.x * 4096;
    long long iend = i0 + 4096; if (iend > E) iend = E;

    if (is64) {
        const long long* dp = (const long long*)eraw + E;
        for (long long i = i0 + t; i < iend; i += 256) {
            int d = (int)dp[i]; d = d < 0 ? 0 : (d >= N ? N - 1 : d);
            atomicAdd(&hist[d >> 9], 1u);
        }
    } else {
        const int* dp = (const int*)eraw + E;
        for (long long i = i0 + t; i < iend; i += 256) {
            int d = dp[i]; d = d < 0 ? 0 : (d >= N ? N - 1 : d);
            atomicAdd(&hist[d >> 9], 1u);
        }
    }
    __syncthreads();
    unsigned int h = hist[t];
    if (h) base[t] = bucket_base[t] + atomicAdd(&bucket_cursor[t], h);
    __syncthreads();
    hist[t] = 0u;
    __syncthreads();

    if (is64) {
        const long long* sp = (const long long*)eraw;
        const long long* dp = sp + E;
        for (long long i = i0 + t; i < iend; i += 256) {
            int s = (int)sp[i]; s = s < 0 ? 0 : (s >= N ? N - 1 : s);
            int d = (int)dp[i]; d = d < 0 ? 0 : (d >= N ? N - 1 : d);
            int bk = d >> 9;
            unsigned int pos = base[bk] + atomicAdd(&hist[bk], 1u);
            recs[pos] = (unsigned)s | ((unsigned)(d & 511) << 20);
        }
    } else {
        const int* sp = (const int*)eraw;
        const int* dp = sp + E;
        for (long long i = i0 + t; i < iend; i += 256) {
            int s = sp[i]; s = s < 0 ? 0 : (s >= N ? N - 1 : s);
            int d = dp[i]; d = d < 0 ? 0 : (d >= N ? N - 1 : d);
            int bk = d >> 9;
            unsigned int pos = base[bk] + atomicAdd(&hist[bk], 1u);
            recs[pos] = (unsigned)s | ((unsigned)(d & 511) << 20);
        }
    }
}

// per-bucket: LDS degree hist over 512 local dsts, LDS scan -> off/degcnt/dinv
// (coalesced), then exact CSR scatter via LDS cursor atomics.
__global__ __launch_bounds__(256) void bucket_fill_kernel(
    const unsigned int* __restrict__ recs, const unsigned int* __restrict__ bucket_base,
    unsigned int* __restrict__ off, unsigned int* __restrict__ degcnt,
    float* __restrict__ dinv, int* __restrict__ csr_src, int N)
{
    __shared__ unsigned int ldeg[512];
    __shared__ unsigned int lscan[256];
    const int t = threadIdx.x;
    const int b = blockIdx.x;
    const int d0 = b << 9;
    const unsigned int rstart = bucket_base[b];
    const unsigned int rend   = bucket_base[b + 1];
    ldeg[t] = 0u; ldeg[t + 256] = 0u;
    __syncthreads();
    for (unsigned int i = rstart + t; i < rend; i += 256)
        atomicAdd(&ldeg[recs[i] >> 20], 1u);
    __syncthreads();
    unsigned int a0 = ldeg[2 * t], a1 = ldeg[2 * t + 1];
    unsigned int ps = a0 + a1;
    lscan[t] = ps;
    __syncthreads();
    for (int o = 1; o < 256; o <<= 1) {
        unsigned int x = (t >= o) ? lscan[t - o] : 0u;
        __syncthreads();
        lscan[t] += x;
        __syncthreads();
    }
    unsigned int ex = lscan[t] - ps;
    unsigned int o0 = rstart + ex;
    unsigned int o1 = o0 + a0;
    int dA = d0 + 2 * t, dB = dA + 1;
    if (dA < N) { off[dA] = o0; degcnt[dA] = a0; dinv[dA] = rsqrtf((float)(a0 + 1u)); }
    if (dB < N) { off[dB] = o1; degcnt[dB] = a1; dinv[dB] = rsqrtf((float)(a1 + 1u)); }
    ldeg[2 * t]     = o0;     // reuse as absolute cursors
    ldeg[2 * t + 1] = o1;
    __syncthreads();
    for (unsigned int i = rstart + t; i < rend; i += 256) {
        unsigned int r = recs[i];
        unsigned int slot = atomicAdd(&ldeg[r >> 20], 1u);
        csr_src[slot] = (int)(r & 0xFFFFFu);
    }
}

__device__ __forceinline__ bf16x8 pack8(float4 a, float4 b) {
    bf16x8 v;
    v[0] = (short)f2bf(a.x); v[1] = (short)f2bf(a.y);
    v[2] = (short)f2bf(a.z); v[3] = (short)f2bf(a.w);
    v[4] = (short)f2bf(b.x); v[5] = (short)f2bf(b.y);
    v[6] = (short)f2bf(b.z); v[7] = (short)f2bf(b.w);
    return v;
}

// GEMM1: hsg[g][r][cc] = bf16( ((xh @ W) * dinv[r])[g*16+cc] ), K=256.
__global__ __launch_bounds__(256) void gemm1_mfma_kernel(
    const float* __restrict__ x, const float* __restrict__ hidden,
    const unsigned short* __restrict__ Wt, const float* __restrict__ dinv,
    unsigned short* __restrict__ hsg, int N)
{
    const int lane = threadIdx.x & 63;
    const int wave = threadIdx.x >> 6;
    const int i16  = lane & 15;
    const int kg   = lane >> 4;          // 0..3
    const int koff = kg * 8;
    const int wrow0 = blockIdx.x * 128 + wave * 32;

    f32x4 acc[2][8];
#pragma unroll
    for (int m = 0; m < 2; ++m)
#pragma unroll
        for (int n = 0; n < 8; ++n) acc[m][n] = (f32x4){0.f, 0.f, 0.f, 0.f};

    int r[2], rl[2];
#pragma unroll
    for (int m = 0; m < 2; ++m) {
        r[m]  = wrow0 + m * 16 + i16;
        rl[m] = r[m] < N ? r[m] : N - 1;
    }

#pragma unroll
    for (int ks = 0; ks < 8; ++ks) {
        const int k0 = ks * 32;
        const float* __restrict__ src = (k0 < 128) ? x : hidden;
        const int kc = (k0 & 127) + koff;
        bf16x8 xf[2];
#pragma unroll
        for (int m = 0; m < 2; ++m) {
            const float* pa = src + (size_t)rl[m] * 128 + kc;
            float4 a = *(const float4*)pa;
            float4 b = *(const float4*)(pa + 4);
            xf[m] = pack8(a, b);
        }
#pragma unroll
        for (int n = 0; n < 8; ++n) {
            bf16x8 wf = *(const bf16x8*)(Wt + (size_t)(n * 16 + i16) * 256 + k0 + koff);
            acc[0][n] = __builtin_amdgcn_mfma_f32_16x16x32_bf16(wf, xf[0], acc[0][n], 0, 0, 0);
            acc[1][n] = __builtin_amdgcn_mfma_f32_16x16x32_bf16(wf, xf[1], acc[1][n], 0, 0, 0);
        }
    }

#pragma unroll
    for (int m = 0; m < 2; ++m) {
        if (r[m] < N) {
            const float s = dinv[r[m]];
#pragma unroll
            for (int n = 0; n < 8; ++n) {     // n is the column group
                s16x4 o;
                o[0] = (short)f2bf(acc[m][n][0] * s);
                o[1] = (short)f2bf(acc[m][n][1] * s);
                o[2] = (short)f2bf(acc[m][n][2] * s);
                o[3] = (short)f2bf(acc[m][n][3] * s);
                *(s16x4*)(hsg + ((size_t)n * N + r[m]) * 16 + kg * 4) = o;
            }
        }
    }
}

// XCD-column-partitioned aggregation.
// group g = blockIdx&7 (round-robins to one XCD); per-XCD working set 3.2MB.
// wave per node; lane = e8*8 + cp: edge-sub e8 (0..7), col-pair cp (0..7).
__global__ __launch_bounds__(256) void aggregate_kernel(
    const unsigned short* __restrict__ hsg, const int* __restrict__ csr_src,
    const unsigned int* __restrict__ off, const unsigned int* __restrict__ degcnt,
    const float* __restrict__ dinv, const float* __restrict__ bmat,
    const float* __restrict__ bias, float* __restrict__ out_nh, int N)
{
    const int g = blockIdx.x & 7;
    const int n = (blockIdx.x >> 3) * 4 + (threadIdx.x >> 6);
    if (n >= N) return;
    const int lane = threadIdx.x & 63;
    const int e8   = lane >> 3;
    const int cp   = lane & 7;
    const unsigned int start = off[n];
    const unsigned int cnt   = degcnt[n];
    const unsigned int* hw = (const unsigned int*)hsg + (size_t)g * N * 8;

    float ax = 0.f, ay = 0.f;
    if (e8 == 0) {                               // self loop
        unsigned int u = hw[(size_t)n * 8 + cp];
        ax = bflo(u); ay = bfhi(u);
    }
    unsigned int base = 0;
    for (; base + 16 <= cnt; base += 16) {       // 16 edges/iter, 2 loads in flight
        int i0 = csr_src[start + base + e8];
        int i1 = csr_src[start + base + 8 + e8];
        unsigned int u0 = hw[(size_t)i0 * 8 + cp];
        unsigned int u1 = hw[(size_t)i1 * 8 + cp];
        ax += bflo(u0) + bflo(u1);
        ay += bfhi(u0) + bfhi(u1);
    }
    for (; base < cnt; base += 8) {
        int e = (int)base + e8;
        if (e < (int)cnt) {
            int i0 = csr_src[start + e];
            unsigned int u0 = hw[(size_t)i0 * 8 + cp];
            ax += bflo(u0); ay += bfhi(u0);
        }
    }
    // reduce over e8 (lane bits 3..5)
    ax += __shfl_xor(ax, 8, 64);  ay += __shfl_xor(ay, 8, 64);
    ax += __shfl_xor(ax, 16, 64); ay += __shfl_xor(ay, 16, 64);
    ax += __shfl_xor(ax, 32, 64); ay += __shfl_xor(ay, 32, 64);

    if (e8 == 0) {
        const int c0 = g * 16 + cp * 2;
        const float dn = dinv[n];
        const float2 bi = *(const float2*)(bias + c0);
        const float2 bm = *(const float2*)(bmat + (size_t)n * 128 + c0);
        float vx = bm.x + ax * dn + bi.x;
        float vy = bm.y + ay * dn + bi.y;
        float nx = 1.0f / (1.0f + __expf(-vx));
        float ny = 1.0f / (1.0f + __expf(-vy));
        *(float2*)(out_nh + (size_t)n * 128 + c0) = make_float2(nx, ny);
    }
}

// GEMM2: o[r][c] = cmat[r][c] + sum_h bf16(nh[r][h]) * V[h][c], K=128.
__global__ __launch_bounds__(256) void gemm2_mfma_kernel(
    const float* __restrict__ nh, const unsigned short* __restrict__ Vt,
    const float* __restrict__ cmat, float* __restrict__ o, int N)
{
    const int lane = threadIdx.x & 63;
    const int wave = threadIdx.x >> 6;
    const int i16  = lane & 15;
    const int kg   = lane >> 4;
    const int koff = kg * 8;
    const int wrow0 = blockIdx.x * 128 + wave * 32;

    f32x4 acc[2][8];
#pragma unroll
    for (int m = 0; m < 2; ++m)
#pragma unroll
        for (int n = 0; n < 8; ++n) acc[m][n] = (f32x4){0.f, 0.f, 0.f, 0.f};

    int r[2], rl[2];
#pragma unroll
    for (int m = 0; m < 2; ++m) {
        r[m]  = wrow0 + m * 16 + i16;
        rl[m] = r[m] < N ? r[m] : N - 1;
    }

#pragma unroll
    for (int ks = 0; ks < 4; ++ks) {
        const int k0 = ks * 32;
        bf16x8 xf[2];
#pragma unroll
        for (int m = 0; m < 2; ++m) {
            const float* pa = nh + (size_t)rl[m] * 128 + k0 + koff;
            float4 a = *(const float4*)pa;
            float4 b = *(const float4*)(pa + 4);
            xf[m] = pack8(a, b);
        }
#pragma unroll
        for (int n = 0; n < 8; ++n) {
            bf16x8 wf = *(const bf16x8*)(Vt + (size_t)(n * 16 + i16) * 128 + k0 + koff);
            acc[0][n] = __builtin_amdgcn_mfma_f32_16x16x32_bf16(wf, xf[0], acc[0][n], 0, 0, 0);
            acc[1][n] = __builtin_amdgcn_mfma_f32_16x16x32_bf16(wf, xf[1], acc[1][n], 0, 0, 0);
        }
    }

#pragma unroll
    for (int m = 0; m < 2; ++m) {
        if (r[m] < N) {
            const float* crow = cmat + (size_t)r[m] * 128;
            float* orow = o + (size_t)r[m] * 128;
#pragma unroll
            for (int n = 0; n < 8; ++n) {
                const int c0 = n * 16 + kg * 4;
                float4 c = *(const float4*)(crow + c0);
                float4 w = make_float4(acc[m][n][0] + c.x, acc[m][n][1] + c.y,
                                       acc[m][n][2] + c.z, acc[m][n][3] + c.w);
                *(float4*)(orow + c0) = w;
            }
        }
    }
}

extern "C" void kernel_launch(void* const* d_in, const int* in_sizes, int n_in,
                              void* d_out, int out_size, void* d_ws, size_t ws_size,
                              hipStream_t stream) {
    const float* x      = (const float*)d_in[0];
    const float* hidden = (const float*)d_in[1];
    const float* W      = (const float*)d_in[2];
    const float* bias   = (const float*)d_in[3];
    const float* bmat   = (const float*)d_in[4];
    const float* V      = (const float*)d_in[5];
    const float* cmat   = (const float*)d_in[6];
    const void*  eraw   = d_in[7];

    const int H = in_sizes[3];                 // 128
    const int F = in_sizes[5] / H;             // 128
    const int N = in_sizes[0] / F;             // 100000  (must be <= 2^20)
    const long long twoE = in_sizes[7];
    const long long E    = twoE / 2;
    const int nbkt = (N + 511) >> 9;           // 196

    // ---- workspace layout ----
    char* p = (char*)d_ws;
    int* flag = (int*)p;                          p += 256;
    unsigned int* bucket_cnt = (unsigned int*)p;  p += 1024;   // [256]
    unsigned int* bucket_cursor = (unsigned int*)p; p += 1024; // [256], contiguous w/ cnt
    unsigned int* bucket_base = (unsigned int*)p; p += 2048;   // [nbkt+1]
    unsigned int* off    = (unsigned int*)p;      p += (size_t)N * 4;
    unsigned int* degcnt = (unsigned int*)p;      p += (size_t)N * 4;
    float* dinv          = (float*)p;             p += (size_t)N * 4;
    unsigned short* Wt   = (unsigned short*)p;    p += 256 * 128 * 2;
    unsigned short* Vt   = (unsigned short*)p;    p += 128 * 128 * 2;
    unsigned int* recs   = (unsigned int*)p;      p += (size_t)E * 4;
    int* csr_src         = (int*)p;               p += (size_t)E * 4;
    unsigned short* hsg  = (unsigned short*)p;    p += (size_t)N * H * 2;  // [8][N][16]

    float* out_o  = (float*)d_out;
    float* out_nh = (float*)d_out + (size_t)N * F;

    // 1. fused setup: Wt/Vt transpose + zero counters + dtype detect
    setup_kernel<<<193, 256, 0, stream>>>(W, V, Wt, Vt, bucket_cnt,
                                          (const unsigned int*)eraw, twoE, flag);
    // 2. bucket counts
    bucket_count_kernel<<<(unsigned)((E + 8191) / 8192), 256, 0, stream>>>(
        eraw, flag, bucket_cnt, E, N);
    // 3. scan -> bucket_base
    bucket_scan_kernel<<<1, 256, 0, stream>>>(bucket_cnt, bucket_base, nbkt, (unsigned)E);
    // 4. partition into bucket regions (packed recs)
    partition_kernel<<<(unsigned)((E + 4095) / 4096), 256, 0, stream>>>(
        eraw, flag, bucket_base, bucket_cursor, recs, E, N);
    // 5. per-bucket CSR fill + off/degcnt/dinv
    bucket_fill_kernel<<<nbkt, 256, 0, stream>>>(recs, bucket_base, off, degcnt,
                                                 dinv, csr_src, N);
    // 6. GEMM1 (MFMA, scaled by dinv, grouped layout)
    gemm1_mfma_kernel<<<(N + 127) / 128, 256, 0, stream>>>(x, hidden, Wt, dinv, hsg, N);
    // 7. aggregate + sigmoid -> new_hidden (f32, d_out)
    aggregate_kernel<<<(unsigned)(((N + 3) / 4) * 8), 256, 0, stream>>>(
        hsg, csr_src, off, degcnt, dinv, bmat, bias, out_nh, N);
    // 8. GEMM2 -> o
    gemm2_mfma_kernel<<<(N + 127) / 128, 256, 0, stream>>>(out_nh, Vt, cmat, out_o, N);
}

// Round 6
// 258.595 us; speedup vs baseline: 1.8024x; 1.8024x over previous
//
#include <hip/hip_runtime.h>

// ---------------------------------------------------------------------------
// ConvRNN GCN cell — bf16-MFMA GEMMs + bucketed counting-sort CSR + gather.
//   1. setup: Wt/Vt bf16 transpose + zero bucket counters + edge dtype detect
//   2. bucket_count: per-block LDS hist of dst>>9 -> bucket_cnt (196 buckets)
//   3. bucket_scan:  exclusive scan -> bucket_base (CSR coords)
//   4. partition:    scatter packed (src|dlocal<<20) recs into bucket regions
//   5. bucket_fill:  per-bucket LDS degree hist + scan -> off/degcnt/dinv
//                    (coalesced) + exact CSR scatter via LDS atomics
//   6. GEMM1 (MFMA): hs16[n][128] = bf16(([x|hid]@W) * dinv[row])
//   7. aggregate (wave/node, 16-deep pipelined gather) -> new_hidden (f32)
//   8. GEMM2 (MFMA): o = cmat + bf16(nh) @ V   (reads nh f32 from d_out)
// NOTE r5 post-mortem: XCD column-partitioning the gather achieved L2/L3
// locality but destroyed memory-level parallelism (2 loads in flight vs 8,
// 8x edge re-read) -> 3.4x slower. MLP > locality for this working set.
// ---------------------------------------------------------------------------

typedef __attribute__((ext_vector_type(8))) short bf16x8;
typedef __attribute__((ext_vector_type(4))) short s16x4;
typedef __attribute__((ext_vector_type(4))) float f32x4;

__device__ __forceinline__ unsigned short f2bf(float f) {
    unsigned int u = __float_as_uint(f);
    unsigned int r = u + 0x7fffu + ((u >> 16) & 1u);   // round-to-nearest-even
    return (unsigned short)(r >> 16);
}
__device__ __forceinline__ float bflo(unsigned int u) { return __uint_as_float(u << 16); }
__device__ __forceinline__ float bfhi(unsigned int u) { return __uint_as_float(u & 0xffff0000u); }

// blocks 0..127: Wt transpose; 128..191: Vt transpose; 192: zero counters + dtype detect
__global__ __launch_bounds__(256) void setup_kernel(
    const float* __restrict__ W, const float* __restrict__ V,
    unsigned short* __restrict__ Wt, unsigned short* __restrict__ Vt,
    unsigned int* __restrict__ bucket_cnt /*512 words: cnt+cursor*/,
    const unsigned int* __restrict__ eraw, long long twoE, int* __restrict__ flag)
{
    __shared__ int nz;
    const int b = blockIdx.x;
    const int t = threadIdx.x;
    if (b < 128) {
        int idx = b * 256 + t;            // 32768 = 256*128
        int c = idx >> 8, k = idx & 255;
        Wt[c * 256 + k] = f2bf(W[k * 128 + c]);
    } else if (b < 192) {
        int j = (b - 128) * 256 + t;      // 16384 = 128*128
        int c = j >> 7, k = j & 127;
        Vt[c * 128 + k] = f2bf(V[k * 128 + c]);
    } else {
        bucket_cnt[t] = 0u;
        bucket_cnt[t + 256] = 0u;
        if (t == 0) nz = 0;
        __syncthreads();
        long long i = 2LL * t + 1;
        if (i < twoE && eraw[i] != 0u) nz = 1;
        __syncthreads();
        if (t == 0) *flag = (nz == 0) ? 1 : 0;
    }
}

// per-block LDS histogram of dst buckets -> global bucket_cnt
__global__ __launch_bounds__(256) void bucket_count_kernel(
    const void* __restrict__ eraw, const int* __restrict__ flag,
    unsigned int* __restrict__ bucket_cnt, long long E, int N)
{
    __shared__ unsigned int hist[256];
    const int t = threadIdx.x;
    hist[t] = 0u;
    __syncthreads();
    const int is64 = *flag;
    long long i0 = (long long)blockIdx.x * 8192;
    long long iend = i0 + 8192; if (iend > E) iend = E;
    if (is64) {
        const long long* dp = (const long long*)eraw + E;
        for (long long i = i0 + t; i < iend; i += 256) {
            int d = (int)dp[i];
            d = d < 0 ? 0 : (d >= N ? N - 1 : d);
            atomicAdd(&hist[d >> 9], 1u);
        }
    } else {
        const int* dp = (const int*)eraw + E;
        for (long long i = i0 + t; i < iend; i += 256) {
            int d = dp[i];
            d = d < 0 ? 0 : (d >= N ? N - 1 : d);
            atomicAdd(&hist[d >> 9], 1u);
        }
    }
    __syncthreads();
    unsigned int h = hist[t];
    if (h) atomicAdd(&bucket_cnt[t], h);
}

// exclusive scan of <=256 bucket counts; base[nbkt] = E
__global__ void bucket_scan_kernel(const unsigned int* __restrict__ cnt,
                                   unsigned int* __restrict__ base,
                                   int nbkt, unsigned int Etot) {
    __shared__ unsigned int s[256];
    int t = threadIdx.x;
    unsigned int v = (t < nbkt) ? cnt[t] : 0u;
    s[t] = v;
    __syncthreads();
    for (int o = 1; o < 256; o <<= 1) {
        unsigned int x = (t >= o) ? s[t - o] : 0u;
        __syncthreads();
        s[t] += x;
        __syncthreads();
    }
    if (t < nbkt) base[t] = s[t] - v;
    if (t == 0) base[nbkt] = Etot;
}

// scatter packed (src | dlocal<<20) records into bucket regions
__global__ __launch_bounds__(256) void partition_kernel(
    const void* __restrict__ eraw, const int* __restrict__ flag,
    const unsigned int* __restrict__ bucket_base,
    unsigned int* __restrict__ bucket_cursor,
    unsigned int* __restrict__ recs, long long E, int N)
{
    __shared__ unsigned int hist[256];
    __shared__ unsigned int base[256];
    const int t = threadIdx.x;
    hist[t] = 0u;
    __syncthreads();
    const int is64 = *flag;
    long long i0 = (long long)blockIdx.x * 4096;
    long long iend = i0 + 4096; if (iend > E) iend = E;

    if (is64) {
        const long long* dp = (const long long*)eraw + E;
        for (long long i = i0 + t; i < iend; i += 256) {
            int d = (int)dp[i]; d = d < 0 ? 0 : (d >= N ? N - 1 : d);
            atomicAdd(&hist[d >> 9], 1u);
        }
    } else {
        const int* dp = (const int*)eraw + E;
        for (long long i = i0 + t; i < iend; i += 256) {
            int d = dp[i]; d = d < 0 ? 0 : (d >= N ? N - 1 : d);
            atomicAdd(&hist[d >> 9], 1u);
        }
    }
    __syncthreads();
    unsigned int h = hist[t];
    if (h) base[t] = bucket_base[t] + atomicAdd(&bucket_cursor[t], h);
    __syncthreads();
    hist[t] = 0u;
    __syncthreads();

    if (is64) {
        const long long* sp = (const long long*)eraw;
        const long long* dp = sp + E;
        for (long long i = i0 + t; i < iend; i += 256) {
            int s = (int)sp[i]; s = s < 0 ? 0 : (s >= N ? N - 1 : s);
            int d = (int)dp[i]; d = d < 0 ? 0 : (d >= N ? N - 1 : d);
            int bk = d >> 9;
            unsigned int pos = base[bk] + atomicAdd(&hist[bk], 1u);
            recs[pos] = (unsigned)s | ((unsigned)(d & 511) << 20);
        }
    } else {
        const int* sp = (const int*)eraw;
        const int* dp = sp + E;
        for (long long i = i0 + t; i < iend; i += 256) {
            int s = sp[i]; s = s < 0 ? 0 : (s >= N ? N - 1 : s);
            int d = dp[i]; d = d < 0 ? 0 : (d >= N ? N - 1 : d);
            int bk = d >> 9;
            unsigned int pos = base[bk] + atomicAdd(&hist[bk], 1u);
            recs[pos] = (unsigned)s | ((unsigned)(d & 511) << 20);
        }
    }
}

// per-bucket: LDS degree hist over 512 local dsts, LDS scan -> off/degcnt/dinv
// (coalesced), then exact CSR scatter via LDS cursor atomics.
__global__ __launch_bounds__(256) void bucket_fill_kernel(
    const unsigned int* __restrict__ recs, const unsigned int* __restrict__ bucket_base,
    unsigned int* __restrict__ off, unsigned int* __restrict__ degcnt,
    float* __restrict__ dinv, int* __restrict__ csr_src, int N)
{
    __shared__ unsigned int ldeg[512];
    __shared__ unsigned int lscan[256];
    const int t = threadIdx.x;
    const int b = blockIdx.x;
    const int d0 = b << 9;
    const unsigned int rstart = bucket_base[b];
    const unsigned int rend   = bucket_base[b + 1];
    ldeg[t] = 0u; ldeg[t + 256] = 0u;
    __syncthreads();
    for (unsigned int i = rstart + t; i < rend; i += 256)
        atomicAdd(&ldeg[recs[i] >> 20], 1u);
    __syncthreads();
    unsigned int a0 = ldeg[2 * t], a1 = ldeg[2 * t + 1];
    unsigned int ps = a0 + a1;
    lscan[t] = ps;
    __syncthreads();
    for (int o = 1; o < 256; o <<= 1) {
        unsigned int x = (t >= o) ? lscan[t - o] : 0u;
        __syncthreads();
        lscan[t] += x;
        __syncthreads();
    }
    unsigned int ex = lscan[t] - ps;
    unsigned int o0 = rstart + ex;
    unsigned int o1 = o0 + a0;
    int dA = d0 + 2 * t, dB = dA + 1;
    if (dA < N) { off[dA] = o0; degcnt[dA] = a0; dinv[dA] = rsqrtf((float)(a0 + 1u)); }
    if (dB < N) { off[dB] = o1; degcnt[dB] = a1; dinv[dB] = rsqrtf((float)(a1 + 1u)); }
    ldeg[2 * t]     = o0;     // reuse as absolute cursors
    ldeg[2 * t + 1] = o1;
    __syncthreads();
    for (unsigned int i = rstart + t; i < rend; i += 256) {
        unsigned int r = recs[i];
        unsigned int slot = atomicAdd(&ldeg[r >> 20], 1u);
        csr_src[slot] = (int)(r & 0xFFFFFu);
    }
}

__device__ __forceinline__ bf16x8 pack8(float4 a, float4 b) {
    bf16x8 v;
    v[0] = (short)f2bf(a.x); v[1] = (short)f2bf(a.y);
    v[2] = (short)f2bf(a.z); v[3] = (short)f2bf(a.w);
    v[4] = (short)f2bf(b.x); v[5] = (short)f2bf(b.y);
    v[6] = (short)f2bf(b.z); v[7] = (short)f2bf(b.w);
    return v;
}

// GEMM1: hs16[r][c] = bf16( (sum_k xh[r][k] * W[k][c]) * dinv[r] ), K=256.
__global__ __launch_bounds__(256) void gemm1_mfma_kernel(
    const float* __restrict__ x, const float* __restrict__ hidden,
    const unsigned short* __restrict__ Wt, const float* __restrict__ dinv,
    unsigned short* __restrict__ hs16, int N)
{
    const int lane = threadIdx.x & 63;
    const int wave = threadIdx.x >> 6;
    const int i16  = lane & 15;
    const int kg   = lane >> 4;          // 0..3
    const int koff = kg * 8;
    const int wrow0 = blockIdx.x * 128 + wave * 32;

    f32x4 acc[2][8];
#pragma unroll
    for (int m = 0; m < 2; ++m)
#pragma unroll
        for (int n = 0; n < 8; ++n) acc[m][n] = (f32x4){0.f, 0.f, 0.f, 0.f};

    int r[2], rl[2];
#pragma unroll
    for (int m = 0; m < 2; ++m) {
        r[m]  = wrow0 + m * 16 + i16;
        rl[m] = r[m] < N ? r[m] : N - 1;
    }

#pragma unroll
    for (int ks = 0; ks < 8; ++ks) {
        const int k0 = ks * 32;
        const float* __restrict__ src = (k0 < 128) ? x : hidden;
        const int kc = (k0 & 127) + koff;
        bf16x8 xf[2];
#pragma unroll
        for (int m = 0; m < 2; ++m) {
            const float* pa = src + (size_t)rl[m] * 128 + kc;
            float4 a = *(const float4*)pa;
            float4 b = *(const float4*)(pa + 4);
            xf[m] = pack8(a, b);
        }
#pragma unroll
        for (int n = 0; n < 8; ++n) {
            bf16x8 wf = *(const bf16x8*)(Wt + (size_t)(n * 16 + i16) * 256 + k0 + koff);
            acc[0][n] = __builtin_amdgcn_mfma_f32_16x16x32_bf16(wf, xf[0], acc[0][n], 0, 0, 0);
            acc[1][n] = __builtin_amdgcn_mfma_f32_16x16x32_bf16(wf, xf[1], acc[1][n], 0, 0, 0);
        }
    }

#pragma unroll
    for (int m = 0; m < 2; ++m) {
        if (r[m] < N) {
            const float s = dinv[r[m]];
            unsigned short* dst = hs16 + (size_t)r[m] * 128;
#pragma unroll
            for (int n = 0; n < 8; ++n) {
                s16x4 o;
                o[0] = (short)f2bf(acc[m][n][0] * s);
                o[1] = (short)f2bf(acc[m][n][1] * s);
                o[2] = (short)f2bf(acc[m][n][2] * s);
                o[3] = (short)f2bf(acc[m][n][3] * s);
                *(s16x4*)(dst + n * 16 + kg * 4) = o;
            }
        }
    }
}

// wave-per-node aggregation; lane owns cols {2*lane, 2*lane+1}.
// 16-deep software-pipelined gather; epilogue loads pre-issued.
__global__ __launch_bounds__(256) void aggregate_kernel(
    const unsigned short* __restrict__ hs16, const int* __restrict__ csr_src,
    const unsigned int* __restrict__ off, const unsigned int* __restrict__ degcnt,
    const float* __restrict__ dinv, const float* __restrict__ bmat,
    const float* __restrict__ bias, float* __restrict__ out_nh, int N)
{
    const int lane = threadIdx.x & 63;
    const int n = blockIdx.x * 4 + (threadIdx.x >> 6);
    if (n >= N) return;
    const unsigned int start = off[n];
    const unsigned int cnt   = degcnt[n];
    const unsigned int* hsw = (const unsigned int*)hs16;   // 2 bf16 per word

    // pre-issue epilogue operands so their latency hides under the gather loop
    const float dn = dinv[n];
    const float2 bi = *(const float2*)(bias + lane * 2);
    const float2 bm = *(const float2*)(bmat + (size_t)n * 128 + lane * 2);

    unsigned int v = hsw[(size_t)n * 64 + lane];           // self loop
    float ax = bflo(v), ay = bfhi(v);

    for (unsigned int base = 0; base < cnt; base += 64) {
        int idx = (base + lane < cnt) ? csr_src[start + base + lane] : 0;
        int m = (int)min(64u, cnt - base);
        int i = 0;
        // 16-wide: 16 independent gathers in flight
        for (; i + 16 <= m; i += 16) {
            unsigned int u[16];
#pragma unroll
            for (int j = 0; j < 16; ++j) {
                int s = __shfl(idx, i + j, 64);
                u[j] = hsw[(size_t)s * 64 + lane];
            }
#pragma unroll
            for (int j = 0; j < 16; ++j) { ax += bflo(u[j]); ay += bfhi(u[j]); }
        }
        for (; i + 4 <= m; i += 4) {
            unsigned int u[4];
#pragma unroll
            for (int j = 0; j < 4; ++j) {
                int s = __shfl(idx, i + j, 64);
                u[j] = hsw[(size_t)s * 64 + lane];
            }
#pragma unroll
            for (int j = 0; j < 4; ++j) { ax += bflo(u[j]); ay += bfhi(u[j]); }
        }
        for (; i < m; ++i) {
            int s = __shfl(idx, i, 64);
            unsigned int u = hsw[(size_t)s * 64 + lane];
            ax += bflo(u); ay += bfhi(u);
        }
    }
    float vx = bm.x + ax * dn + bi.x;
    float vy = bm.y + ay * dn + bi.y;
    float nx = 1.0f / (1.0f + __expf(-vx));
    float ny = 1.0f / (1.0f + __expf(-vy));
    *(float2*)(out_nh + (size_t)n * 128 + lane * 2) = make_float2(nx, ny);
}

// GEMM2: o[r][c] = cmat[r][c] + sum_h bf16(nh[r][h]) * V[h][c], K=128.
__global__ __launch_bounds__(256) void gemm2_mfma_kernel(
    const float* __restrict__ nh, const unsigned short* __restrict__ Vt,
    const float* __restrict__ cmat, float* __restrict__ o, int N)
{
    const int lane = threadIdx.x & 63;
    const int wave = threadIdx.x >> 6;
    const int i16  = lane & 15;
    const int kg   = lane >> 4;
    const int koff = kg * 8;
    const int wrow0 = blockIdx.x * 128 + wave * 32;

    f32x4 acc[2][8];
#pragma unroll
    for (int m = 0; m < 2; ++m)
#pragma unroll
        for (int n = 0; n < 8; ++n) acc[m][n] = (f32x4){0.f, 0.f, 0.f, 0.f};

    int r[2], rl[2];
#pragma unroll
    for (int m = 0; m < 2; ++m) {
        r[m]  = wrow0 + m * 16 + i16;
        rl[m] = r[m] < N ? r[m] : N - 1;
    }

#pragma unroll
    for (int ks = 0; ks < 4; ++ks) {
        const int k0 = ks * 32;
        bf16x8 xf[2];
#pragma unroll
        for (int m = 0; m < 2; ++m) {
            const float* pa = nh + (size_t)rl[m] * 128 + k0 + koff;
            float4 a = *(const float4*)pa;
            float4 b = *(const float4*)(pa + 4);
            xf[m] = pack8(a, b);
        }
#pragma unroll
        for (int n = 0; n < 8; ++n) {
            bf16x8 wf = *(const bf16x8*)(Vt + (size_t)(n * 16 + i16) * 128 + k0 + koff);
            acc[0][n] = __builtin_amdgcn_mfma_f32_16x16x32_bf16(wf, xf[0], acc[0][n], 0, 0, 0);
            acc[1][n] = __builtin_amdgcn_mfma_f32_16x16x32_bf16(wf, xf[1], acc[1][n], 0, 0, 0);
        }
    }

#pragma unroll
    for (int m = 0; m < 2; ++m) {
        if (r[m] < N) {
            const float* crow = cmat + (size_t)r[m] * 128;
            float* orow = o + (size_t)r[m] * 128;
#pragma unroll
            for (int n = 0; n < 8; ++n) {
                const int c0 = n * 16 + kg * 4;
                float4 c = *(const float4*)(crow + c0);
                float4 w = make_float4(acc[m][n][0] + c.x, acc[m][n][1] + c.y,
                                       acc[m][n][2] + c.z, acc[m][n][3] + c.w);
                *(float4*)(orow + c0) = w;
            }
        }
    }
}

extern "C" void kernel_launch(void* const* d_in, const int* in_sizes, int n_in,
                              void* d_out, int out_size, void* d_ws, size_t ws_size,
                              hipStream_t stream) {
    const float* x      = (const float*)d_in[0];
    const float* hidden = (const float*)d_in[1];
    const float* W      = (const float*)d_in[2];
    const float* bias   = (const float*)d_in[3];
    const float* bmat   = (const float*)d_in[4];
    const float* V      = (const float*)d_in[5];
    const float* cmat   = (const float*)d_in[6];
    const void*  eraw   = d_in[7];

    const int H = in_sizes[3];                 // 128
    const int F = in_sizes[5] / H;             // 128
    const int N = in_sizes[0] / F;             // 100000  (must be <= 2^20)
    const long long twoE = in_sizes[7];
    const long long E    = twoE / 2;
    const int nbkt = (N + 511) >> 9;           // 196

    // ---- workspace layout ----
    char* p = (char*)d_ws;
    int* flag = (int*)p;                          p += 256;
    unsigned int* bucket_cnt = (unsigned int*)p;  p += 1024;   // [256]
    unsigned int* bucket_cursor = (unsigned int*)p; p += 1024; // [256], contiguous w/ cnt
    unsigned int* bucket_base = (unsigned int*)p; p += 2048;   // [nbkt+1]
    unsigned int* off    = (unsigned int*)p;      p += (size_t)N * 4;
    unsigned int* degcnt = (unsigned int*)p;      p += (size_t)N * 4;
    float* dinv          = (float*)p;             p += (size_t)N * 4;
    unsigned short* Wt   = (unsigned short*)p;    p += 256 * 128 * 2;
    unsigned short* Vt   = (unsigned short*)p;    p += 128 * 128 * 2;
    unsigned int* recs   = (unsigned int*)p;      p += (size_t)E * 4;
    int* csr_src         = (int*)p;               p += (size_t)E * 4;
    unsigned short* hs16 = (unsigned short*)p;    p += (size_t)N * H * 2;

    float* out_o  = (float*)d_out;
    float* out_nh = (float*)d_out + (size_t)N * F;

    // 1. fused setup: Wt/Vt transpose + zero counters + dtype detect
    setup_kernel<<<193, 256, 0, stream>>>(W, V, Wt, Vt, bucket_cnt,
                                          (const unsigned int*)eraw, twoE, flag);
    // 2. bucket counts
    bucket_count_kernel<<<(unsigned)((E + 8191) / 8192), 256, 0, stream>>>(
        eraw, flag, bucket_cnt, E, N);
    // 3. scan -> bucket_base
    bucket_scan_kernel<<<1, 256, 0, stream>>>(bucket_cnt, bucket_base, nbkt, (unsigned)E);
    // 4. partition into bucket regions (packed recs)
    partition_kernel<<<(unsigned)((E + 4095) / 4096), 256, 0, stream>>>(
        eraw, flag, bucket_base, bucket_cursor, recs, E, N);
    // 5. per-bucket CSR fill + off/degcnt/dinv
    bucket_fill_kernel<<<nbkt, 256, 0, stream>>>(recs, bucket_base, off, degcnt,
                                                 dinv, csr_src, N);
    // 6. GEMM1 (MFMA, scaled by dinv)
    gemm1_mfma_kernel<<<(N + 127) / 128, 256, 0, stream>>>(x, hidden, Wt, dinv, hs16, N);
    // 7. aggregate + sigmoid -> new_hidden (f32, d_out)
    aggregate_kernel<<<(N + 3) / 4, 256, 0, stream>>>(hs16, csr_src, off, degcnt, dinv,
                                                      bmat, bias, out_nh, N);
    // 8. GEMM2 -> o
    gemm2_mfma_kernel<<<(N + 127) / 128, 256, 0, stream>>>(out_nh, Vt, cmat, out_o, N);
}